// Round 1
// baseline (69.173 us; speedup 1.0000x reference)
//
#include <hip/hip_runtime.h>
#include <hip/hip_bf16.h>

// Shapes (fixed by setup_inputs): x [16,64,256,256] f32, haar [256,256] f32.
// out [16,64,128,128] f32.  out[b,c2,i2,j2] = res[b, i2&63, 4*c2+(i2>>6), j2],
// res = X @ (haar@haar).  Only rows i%4<2 and cols j<128 of res are needed.

typedef __attribute__((ext_vector_type(8))) short bf16x8;
typedef __attribute__((ext_vector_type(4))) float f32x4;

// ---------------------------------------------------------------- H2^T (bf16)
// h2t[n*256 + k] = bf16( sum_t haar[k][t] * haar[t][n] ),  n in [0,128)
__global__ void h2t_kernel(const float* __restrict__ haar,
                           unsigned short* __restrict__ h2t) {
    __shared__ float rowk[256];
    const int k = blockIdx.x;    // 0..255
    const int n = threadIdx.x;   // 0..127
    rowk[n]       = haar[k * 256 + n];
    rowk[n + 128] = haar[k * 256 + n + 128];
    __syncthreads();
    float acc = 0.f;
#pragma unroll 8
    for (int t = 0; t < 256; ++t)
        acc = fmaf(rowk[t], haar[t * 256 + n], acc);   // coalesced across n
    __hip_bfloat16 bv = __float2bfloat16(acc);
    h2t[n * 256 + k] = *reinterpret_cast<unsigned short*>(&bv);
}

// ---------------------------------------------------------------- main GEMM
static __device__ inline bf16x8 cvt8(float4 a, float4 b) {
    union { bf16x8 v; __hip_bfloat16 h[8]; } u;
    u.h[0] = __float2bfloat16(a.x);
    u.h[1] = __float2bfloat16(a.y);
    u.h[2] = __float2bfloat16(a.z);
    u.h[3] = __float2bfloat16(a.w);
    u.h[4] = __float2bfloat16(b.x);
    u.h[5] = __float2bfloat16(b.y);
    u.h[6] = __float2bfloat16(b.z);
    u.h[7] = __float2bfloat16(b.w);
    return u.v;
}

// One block per (b,c): 128 selected rows x 128 cols, K=256.
// 4 waves in a 2x2 grid of 64x64 quadrants; 4x4 fragments of 16x16x32 each.
__global__ void wavelet_gemm_kernel(const float* __restrict__ x,
                                    const unsigned short* __restrict__ h2t,
                                    float* __restrict__ out) {
    const int blk  = blockIdx.x;       // b*64 + c
    const int c    = blk & 63;
    const int b    = blk >> 6;
    const int tid  = threadIdx.x;
    const int lane = tid & 63;
    const int wid  = tid >> 6;         // 0..3
    const int wr   = wid >> 1;         // row half of block tile
    const int wc   = wid & 1;          // col half
    const int lr   = lane & 15;        // fragment row (A) / col (B)
    const int lg   = lane >> 4;        // k sub-group (0..3)

    const float* xb = x + (size_t)blk * 65536;  // x[b][c]

    // Per-fragment base pointers (k-offset lg*8; same mapping for A and B so
    // any internal hw k-permutation cancels).
    const float* ap[4];
#pragma unroll
    for (int fa = 0; fa < 4; ++fa) {
        int m = wr * 64 + fa * 16 + lr;          // selected-row index 0..127
        int i = ((m >> 1) << 2) | (m & 1);       // actual x row (i%4 in {0,1})
        ap[fa] = xb + i * 256 + lg * 8;
    }
    const unsigned short* bp[4];
#pragma unroll
    for (int fb = 0; fb < 4; ++fb) {
        int n = wc * 64 + fb * 16 + lr;          // output col 0..127
        bp[fb] = h2t + n * 256 + lg * 8;
    }

    f32x4 acc[4][4] = {};

#pragma unroll 2
    for (int k0 = 0; k0 < 256; k0 += 32) {
        bf16x8 aF[4], bF[4];
#pragma unroll
        for (int fa = 0; fa < 4; ++fa) {
            float4 v0 = *reinterpret_cast<const float4*>(ap[fa] + k0);
            float4 v1 = *reinterpret_cast<const float4*>(ap[fa] + k0 + 4);
            aF[fa] = cvt8(v0, v1);
        }
#pragma unroll
        for (int fb = 0; fb < 4; ++fb)
            bF[fb] = *reinterpret_cast<const bf16x8*>(bp[fb] + k0);
#pragma unroll
        for (int fa = 0; fa < 4; ++fa)
#pragma unroll
            for (int fb = 0; fb < 4; ++fb)
                acc[fa][fb] = __builtin_amdgcn_mfma_f32_16x16x32_bf16(
                    aF[fa], bF[fb], acc[fa][fb], 0, 0, 0);
    }

    // Epilogue: C/D layout (m89-verified): col = lane&15, row = (lane>>4)*4+r.
    // Scatter through the reference's reshape scramble:
    //   out[((b*64 + (m>>1))*128 + (m&1)*64 + c)*128 + j]
#pragma unroll
    for (int fa = 0; fa < 4; ++fa) {
        const int mbase = wr * 64 + fa * 16 + lg * 4;
#pragma unroll
        for (int fb = 0; fb < 4; ++fb) {
            const int j = wc * 64 + fb * 16 + lr;
#pragma unroll
            for (int r = 0; r < 4; ++r) {
                const int m = mbase + r;
                const size_t oidx =
                    (((size_t)b * 64 + (m >> 1)) * 128 + (m & 1) * 64 + c) * 128 + j;
                out[oidx] = acc[fa][fb][r];
            }
        }
    }
}

extern "C" void kernel_launch(void* const* d_in, const int* in_sizes, int n_in,
                              void* d_out, int out_size, void* d_ws, size_t ws_size,
                              hipStream_t stream) {
    const float* x    = (const float*)d_in[0];
    const float* haar = (const float*)d_in[1];
    float* out = (float*)d_out;
    unsigned short* h2t = (unsigned short*)d_ws;  // 128*256 bf16 = 64 KB

    h2t_kernel<<<dim3(256), dim3(128), 0, stream>>>(haar, h2t);
    wavelet_gemm_kernel<<<dim3(1024), dim3(256), 0, stream>>>(x, h2t, out);
}